// Round 9
// baseline (75.734 us; speedup 1.0000x reference)
//
#include <hip/hip_runtime.h>
#include <hip/hip_bf16.h>

typedef short short4v __attribute__((ext_vector_type(4)));
typedef short short8v __attribute__((ext_vector_type(8)));
typedef float float4v __attribute__((ext_vector_type(4)));
typedef __bf16 bf16x8 __attribute__((ext_vector_type(8)));

typedef __attribute__((address_space(1))) const unsigned int g_uint;
typedef __attribute__((address_space(3))) unsigned int lds_uint;

__device__ __forceinline__ unsigned short f2bf(float f) {
    union { float f; unsigned int i; } t;
    t.f = f;
    unsigned int u = t.i;
    u += 0x7fffu + ((u >> 16) & 1u);   // round-to-nearest-even
    return (unsigned short)(u >> 16);
}

__device__ __forceinline__ short bfcast(float f) {
    __bf16 h = (__bf16)f;               // native cvt (compiler fuses pairs into v_cvt_pk_bf16_f32)
    return __builtin_bit_cast(short, h);
}

// v_exp_f32 computes 2^x; s_nop covers the trans->valu wait state
__device__ __forceinline__ float fast_exp2(float x) {
    float r;
    asm("v_exp_f32 %0, %1\n\ts_nop 0" : "=v"(r) : "v"(x));
    return r;
}

// async global->LDS, 16B per lane; lds dest is wave-uniform base + lane*16
__device__ __forceinline__ void gload_lds16(const unsigned short* g, unsigned short* l) {
    __builtin_amdgcn_global_load_lds((g_uint*)g, (lds_uint*)l, 16, 0, 0);
}

// read 8 contiguous bf16 (b128) from a swizzled [64][64] u16 tile:
// element (row, 8*slot + i) lives at u16 offset row*64 + ((slot ^ (row&7))<<3) + i
__device__ __forceinline__ bf16x8 frag128(const unsigned short* t, int row, int slot) {
    return *reinterpret_cast<const bf16x8*>(
        reinterpret_cast<const char*>(t) + row * 128 + (((slot ^ (row & 7)) << 4)));
}

__device__ __forceinline__ float4v mfma32(bf16x8 a, bf16x8 b, float4v c) {
    return __builtin_amdgcn_mfma_f32_16x16x32_bf16(a, b, c, 0, 0, 0);
}

// ---------------------------------------------------------------------------
// Kernel 0: weights f32 -> bf16
// ---------------------------------------------------------------------------
__global__ __launch_bounds__(256) void prep_kernel(const float* __restrict__ wq,
                                                   const float* __restrict__ wo,
                                                   unsigned short* __restrict__ wqb,
                                                   unsigned short* __restrict__ wob) {
    int i = blockIdx.x * 256 + threadIdx.x;   // 262144 total
    if (i < 196608) wqb[i] = f2bf(wq[i]);
    else            wob[i - 196608] = f2bf(wo[i - 196608]);
}

// ---------------------------------------------------------------------------
// Kernel 1: fused channel-LN + QKV GEMM (+ L2-norm + attention-ready layouts).
// 1D grid 3072, XCD-swizzled.  Block computes LN of its 64-pixel X-tile
// directly into LDS (swizzled frag128 layout), stages the full W k-range
// upfront, then runs a barrier-free 4-step k-loop.
// m<4: qhat (scaled by 8*log2e); m 4..7: khatT swizzled tiles;
// m>=8: vperm swizzled tiles.
// ---------------------------------------------------------------------------
__global__ __launch_bounds__(256) void ln_qkv_gemm(const float* __restrict__ x,
                                                   const float* __restrict__ gam,
                                                   const unsigned short* __restrict__ wqkv,
                                                   unsigned short* __restrict__ qhat,
                                                   unsigned short* __restrict__ khatT,
                                                   unsigned short* __restrict__ vperm) {
    __shared__ __align__(16) unsigned short sW[16384];   // [4 k-chunks][64][64] swizzled
    __shared__ __align__(16) unsigned short sX[16384];
    const int tid = threadIdx.x, lane = tid & 63, w = tid >> 6;
    const int l16 = lane & 15, g = lane >> 4;
    const int id = blockIdx.x;
    const int xcd = id & 7, sIdx = id >> 3;
    const int m = sIdx % 12, tq = sIdx / 12;
    const int t = xcd + (tq << 3);            // 0..255 X-tile index
    const int pb = t & 15, b = t >> 4;

    const unsigned short* Wbase = wqkv + m * 64 * 256;
    const int srow = lane >> 3, sslot = lane & 7;

    // stage ALL of W (64 rows x 256 k) upfront: 8 gload_lds per wave
    #pragma unroll
    for (int ks = 0; ks < 4; ++ks)
        #pragma unroll
        for (int ii = 0; ii < 2; ++ii) {
            int inst = w + 4 * ii;
            int row = inst * 8 + srow;
            int src = row * 256 + ks * 64 + 8 * (sslot ^ (row & 7));
            gload_lds16(Wbase + src, &sW[ks * 4096 + inst * 512]);
        }

    // ---- channel LayerNorm of the 64-pixel X-tile, written into sX ----
    float* red = (float*)sX;                  // overlay [2][4][64] floats (2 KB)
    const int p = tid & 63, cg = tid >> 6;
    const float* xb = x + ((size_t)b << 18) + pb * 64 + p;

    float v[64];
    float s = 0.f, q = 0.f;
    #pragma unroll
    for (int cc = 0; cc < 64; ++cc) {
        v[cc] = xb[(cg * 64 + cc) << 10];
        s += v[cc]; q += v[cc] * v[cc];
    }
    red[(0 * 4 + cg) * 64 + p] = s;
    red[(1 * 4 + cg) * 64 + p] = q;
    __syncthreads();
    float ts = 0.f, tqv = 0.f;
    #pragma unroll
    for (int k = 0; k < 4; ++k) {
        ts  += red[(0 * 4 + k) * 64 + p];
        tqv += red[(1 * 4 + k) * 64 + p];
    }
    float mean = ts * (1.f / 256.f);
    float var  = tqv * (1.f / 256.f) - mean * mean;
    float rstd = rsqrtf(var + 1e-5f);
    float bias = -mean * rstd;
    __syncthreads();   // red consumed; sX may now be overwritten

    // thread (p, cg) fills row p of k-chunk cg: 8 swizzled b128 writes
    {
        unsigned short* xrow = &sX[cg * 4096 + p * 64];
        #pragma unroll
        for (int sl = 0; sl < 8; ++sl) {
            union { uint4 u; unsigned short h[8]; } pk;
            #pragma unroll
            for (int j = 0; j < 8; ++j)
                pk.h[j] = f2bf(fmaf(v[sl * 8 + j], rstd, bias) * gam[cg * 64 + sl * 8 + j]);
            *reinterpret_cast<uint4*>(xrow + ((sl ^ (p & 7)) << 3)) = pk.u;
        }
    }
    __syncthreads();   // xn visible; implicit vmcnt(0) drain covers W staging

    // ---- barrier-free k-loop ----
    float4v acc[4] = {{0,0,0,0},{0,0,0,0},{0,0,0,0},{0,0,0,0}};
    const bool qk = (m < 8);
    #pragma unroll
    for (int ks = 0; ks < 4; ++ks) {
        const unsigned short* Wt = &sW[ks * 4096];
        const unsigned short* Xt = &sX[ks * 4096];
        #pragma unroll
        for (int kk = 0; kk < 2; ++kk) {
            bf16x8 aF = frag128(qk ? Xt : Wt, 16 * w + l16, 4 * kk + g);
            #pragma unroll
            for (int jt = 0; jt < 4; ++jt) {
                bf16x8 bF = frag128(qk ? Wt : Xt, 16 * jt + l16, 4 * kk + g);
                acc[jt] = mfma32(aF, bF, acc[jt]);
            }
        }
    }

    if (qk) {
        // D[pix = pb*64 + 16w + 4g + r][d(head) = 16jt + l16]; l2-norm over d
        float rn[4];
        #pragma unroll
        for (int r = 0; r < 4; ++r) {
            float ss = acc[0][r]*acc[0][r] + acc[1][r]*acc[1][r]
                     + acc[2][r]*acc[2][r] + acc[3][r]*acc[3][r];
            ss += __shfl_xor(ss, 1, 64);
            ss += __shfl_xor(ss, 2, 64);
            ss += __shfl_xor(ss, 4, 64);
            ss += __shfl_xor(ss, 8, 64);
            rn[r] = rsqrtf(fmaxf(ss, 1e-24f));
        }
        int h = m & 3;
        int bh = b * 4 + h;
        if (m < 4) {
            // fold 8*log2(e) so attention can use p = exp2(st) with no bias
            unsigned short* qb = qhat + ((size_t)bh << 16) + (size_t)(pb * 64 + 16 * w) * 64;
            #pragma unroll
            for (int jt = 0; jt < 4; ++jt)
                #pragma unroll
                for (int r = 0; r < 4; ++r)
                    qb[(4 * g + r) * 64 + 16 * jt + l16] =
                        f2bf(acc[jt][r] * (rn[r] * 11.541560327111707f));
        } else {
            // swizzled K tile: element (j, d) at j*64 + ((d>>3 ^ (j&7))<<3) + (d&7)
            unsigned short* kb = khatT + ((size_t)(bh * 16 + pb)) * 4096;
            #pragma unroll
            for (int jt = 0; jt < 4; ++jt)
                #pragma unroll
                for (int r = 0; r < 4; ++r) {
                    int j = 16 * w + 4 * g + r;
                    int d = 16 * jt + l16;
                    kb[j * 64 + (((d >> 3) ^ (j & 7)) << 3) + (d & 7)] =
                        f2bf(acc[jt][r] * rn[r]);
                }
        }
    } else {
        // V tile [d][colperm(j)] with same XOR swizzle on the 16B slot
        int bh = b * 4 + (m - 8);
        unsigned short* vb = vperm + ((size_t)(bh * 16 + pb)) * 4096;
        #pragma unroll
        for (int jt = 0; jt < 4; ++jt) {
            int cphi = (l16 >> 2) * 2 + (jt >> 1);       // 16B-slot index of colperm(j)
            int cplo = (jt & 1) * 4 + (l16 & 3);         // position within slot
            #pragma unroll
            for (int r = 0; r < 4; ++r) {
                int d = 16 * w + 4 * g + r;
                vb[d * 64 + ((cphi ^ (d & 7)) << 3) + cplo] = f2bf(acc[jt][r]);
            }
        }
    }
}

// ---------------------------------------------------------------------------
// Kernel 2: flash attention — r6's proven structure, verbatim.
// grid 512 XCD-swizzled, 512 threads = 8 waves; wave owns one 16-query i-tile.
// K+V tile (16 KB) staged once per block, double-buffered, stage->sync.
// Fixed-max softmax (q pre-scaled by 8*log2e): p = exp2(st), no rescale.
// ---------------------------------------------------------------------------
__global__ __launch_bounds__(512, 4) void attn_kernel(const unsigned short* __restrict__ qhat,
                                                      const unsigned short* __restrict__ khatT,
                                                      const unsigned short* __restrict__ vperm,
                                                      unsigned short* __restrict__ oT) {
    __shared__ __align__(16) unsigned short smem[16384];   // 2 x (K 4096 | V 4096)
    const int tid = threadIdx.x, lane = tid & 63, w = tid >> 6;
    const int l16 = lane & 15, g = lane >> 4;
    const int id = blockIdx.x;
    const int sIdx = id >> 3;
    const int bh = (id & 7) * 8 + (sIdx >> 3);
    const int qb = sIdx & 7;
    const int b = bh >> 2, h = bh & 3;

    const unsigned short* Qg = qhat + ((size_t)bh << 16) + (size_t)(qb * 128) * 64;
    const unsigned short* Kt = khatT + ((size_t)(bh * 16)) * 4096;
    const unsigned short* Vt = vperm + ((size_t)(bh * 16)) * 4096;

    // Q fragment (B-operand of K=32 mfma): col i = l16 of this wave's i-tile
    bf16x8 bq[2];
    #pragma unroll
    for (int ds = 0; ds < 2; ++ds)
        bq[ds] = *reinterpret_cast<const bf16x8*>(
            Qg + (16 * w + l16) * 64 + 32 * ds + 8 * g);

    auto stage = [&](int buf, int t) {      // 2 gloads per wave
        unsigned short* kb = &smem[buf * 8192 + w * 512];
        unsigned short* vb = &smem[buf * 8192 + 4096 + w * 512];
        gload_lds16(Kt + t * 4096 + w * 512 + lane * 8, kb);
        gload_lds16(Vt + t * 4096 + w * 512 + lane * 8, vb);
    };

    float lsum = 0.f;
    float4v oacc[4] = {};

    stage(0, 0);
    __syncthreads();

    for (int t = 0; t < 16; ++t) {
        const unsigned short* kb = &smem[(t & 1) * 8192];
        const unsigned short* vb = kb + 4096;
        if (t < 15) stage((t + 1) & 1, t + 1);   // issue next tile's loads early

        // S^T[j][i] = sum_d K[j][d] Q^T[d][i]
        float4v st[4] = {};
        #pragma unroll
        for (int ds = 0; ds < 2; ++ds) {
            bf16x8 ak[4];
            #pragma unroll
            for (int jt = 0; jt < 4; ++jt)
                ak[jt] = frag128(kb, 16 * jt + l16, 4 * ds + g);
            __builtin_amdgcn_s_setprio(1);
            #pragma unroll
            for (int jt = 0; jt < 4; ++jt)
                st[jt] = mfma32(ak[jt], bq[ds], st[jt]);
            __builtin_amdgcn_s_setprio(0);
        }

        // V fragment ds_reads issued before softmax; exp hides their latency
        short8v vv[4][2];
        #pragma unroll
        for (int dt = 0; dt < 4; ++dt) {
            int row = 16 * dt + l16;
            #pragma unroll
            for (int q = 0; q < 2; ++q)
                vv[dt][q] = *reinterpret_cast<const short8v*>(
                    reinterpret_cast<const char*>(vb) + row * 128 +
                    (((2 * g + q) ^ (row & 7)) << 4));
        }

        // fixed-max softmax: p = exp2(st)
        short4v pf[4];
        #pragma unroll
        for (int jt = 0; jt < 4; ++jt) {
            float p0 = fast_exp2(st[jt][0]);
            float p1 = fast_exp2(st[jt][1]);
            float p2 = fast_exp2(st[jt][2]);
            float p3 = fast_exp2(st[jt][3]);
            lsum += (p0 + p1) + (p2 + p3);
            short4v tt;
            tt[0] = bfcast(p0); tt[1] = bfcast(p1);
            tt[2] = bfcast(p2); tt[3] = bfcast(p3);
            pf[jt] = tt;
        }

        // O^T[d][i] += V^T[d][j] P^T[j][i]
        __builtin_amdgcn_s_setprio(1);
        #pragma unroll
        for (int dt = 0; dt < 4; ++dt)
            #pragma unroll
            for (int q = 0; q < 2; ++q) {
                short4v lo = __builtin_shufflevector(vv[dt][q], vv[dt][q], 0, 1, 2, 3);
                short4v hi = __builtin_shufflevector(vv[dt][q], vv[dt][q], 4, 5, 6, 7);
                oacc[dt] = __builtin_amdgcn_mfma_f32_16x16x16bf16_1k(
                    lo, pf[2 * q], oacc[dt], 0, 0, 0);
                oacc[dt] = __builtin_amdgcn_mfma_f32_16x16x16bf16_1k(
                    hi, pf[2 * q + 1], oacc[dt], 0, 0, 0);
            }
        __builtin_amdgcn_s_setprio(0);

        __syncthreads();   // buf consumed; next iter's stage may overwrite it
    }

    // softmax denominator across the 4 lane-groups sharing column i
    lsum += __shfl_xor(lsum, 16, 64);
    lsum += __shfl_xor(lsum, 32, 64);
    float inv = 1.f / lsum;

    // transpose O through LDS (reuse smem) -> O_T[pix][h*64+d]
    unsigned short* OL = smem;   // [128][72] u16
    {
        int irow = 16 * w + l16;
        #pragma unroll
        for (int dt = 0; dt < 4; ++dt)
            #pragma unroll
            for (int r = 0; r < 4; ++r)
                OL[irow * 72 + 16 * dt + 4 * g + r] = f2bf(oacc[dt][r] * inv);
    }
    __syncthreads();
    {
        int row = tid >> 2, q4 = tid & 3;
        unsigned short* dst = oT + (((size_t)b << 10) + qb * 128 + row) * 256 + h * 64 + q4 * 16;
        const unsigned short* src = OL + row * 72 + q4 * 16;
        *reinterpret_cast<uint4*>(dst)     = *reinterpret_cast<const uint4*>(src);
        *reinterpret_cast<uint4*>(dst + 8) = *reinterpret_cast<const uint4*>(src + 8);
    }
}

// ---------------------------------------------------------------------------
// Kernel 3: out projection + residual.  1D grid 1024, XCD-swizzled.
// Full K=256 staged upfront (W 32 KB + X 32 KB), one barrier, barrier-free
// k-loop.
// ---------------------------------------------------------------------------
__global__ __launch_bounds__(256) void out_gemm(const unsigned short* __restrict__ oT,
                                                const unsigned short* __restrict__ wout,
                                                const float* __restrict__ x,
                                                float* __restrict__ out) {
    __shared__ __align__(16) unsigned short sW[16384];
    __shared__ __align__(16) unsigned short sX[16384];
    const int tid = threadIdx.x, lane = tid & 63, w = tid >> 6;
    const int l16 = lane & 15, g = lane >> 4;
    const int id = blockIdx.x;
    const int xcd = id & 7, sIdx = id >> 3;   // sIdx 0..127
    const int m = sIdx & 3, tq = sIdx >> 2;
    const int t = xcd + (tq << 3);
    const int pb = t & 15, b = t >> 4;

    const unsigned short* Wbase = wout + m * 64 * 256;
    const unsigned short* Xbase = oT + (((size_t)b << 10) + pb * 64) * 256;

    const int srow = lane >> 3, sslot = lane & 7;

    // stage ALL of W and X upfront: 16 gload_lds per wave
    #pragma unroll
    for (int ks = 0; ks < 4; ++ks)
        #pragma unroll
        for (int ii = 0; ii < 2; ++ii) {
            int inst = w + 4 * ii;
            int row = inst * 8 + srow;
            int src = row * 256 + ks * 64 + 8 * (sslot ^ (row & 7));
            gload_lds16(Wbase + src, &sW[ks * 4096 + inst * 512]);
            gload_lds16(Xbase + src, &sX[ks * 4096 + inst * 512]);
        }
    __syncthreads();   // implicit vmcnt(0) drain: all staging complete

    float4v acc[4] = {{0,0,0,0},{0,0,0,0},{0,0,0,0},{0,0,0,0}};
    #pragma unroll
    for (int ks = 0; ks < 4; ++ks) {
        const unsigned short* Wt = &sW[ks * 4096];
        const unsigned short* Xt = &sX[ks * 4096];
        #pragma unroll
        for (int kk = 0; kk < 2; ++kk) {
            bf16x8 aF = frag128(Wt, 16 * w + l16, 4 * kk + g);
            #pragma unroll
            for (int jt = 0; jt < 4; ++jt) {
                bf16x8 bF = frag128(Xt, 16 * jt + l16, 4 * kk + g);
                acc[jt] = mfma32(aF, bF, acc[jt]);
            }
        }
    }

    #pragma unroll
    for (int jt = 0; jt < 4; ++jt)
        #pragma unroll
        for (int r = 0; r < 4; ++r) {
            size_t idx = ((size_t)b << 18) + (size_t)(m * 64 + 16 * w + 4 * g + r) * 1024
                       + pb * 64 + 16 * jt + l16;
            out[idx] = acc[jt][r] + x[idx];
        }
}

// ---------------------------------------------------------------------------
extern "C" void kernel_launch(void* const* d_in, const int* in_sizes, int n_in,
                              void* d_out, int out_size, void* d_ws, size_t ws_size,
                              hipStream_t stream) {
    const float* x  = (const float*)d_in[0];
    const float* g  = (const float*)d_in[1];
    const float* wq = (const float*)d_in[2];
    const float* wo = (const float*)d_in[3];
    float* out = (float*)d_out;

    char* ws = (char*)d_ws;
    // ws layout:
    //   [0, 8.4MB)        oT bf16 [16][1024][256] (attention output, transposed)
    //   [8.4, 16.8MB)     qhat bf16 [bh=64][1024][64]  (scaled by 8*log2e)
    //   [16.8, 25.2MB)    khatT swizzled tiles [bh=64][16][64*64]
    //   [25.2, 33.6MB)    vperm swizzled tiles [bh=64][16][64*64]
    //   [33.6MB, ...)     w_qkv bf16, w_out bf16
    unsigned short* oT    = (unsigned short*)(ws);
    unsigned short* qhat  = (unsigned short*)(ws + 8388608);
    unsigned short* khatT = (unsigned short*)(ws + 16777216);
    unsigned short* vperm = (unsigned short*)(ws + 25165824);
    unsigned short* wqb   = (unsigned short*)(ws + 33554432);
    unsigned short* wob   = (unsigned short*)(ws + 33947648);

    prep_kernel<<<1024, 256, 0, stream>>>(wq, wo, wqb, wob);
    ln_qkv_gemm<<<3072, 256, 0, stream>>>(x, g, wqb, qhat, khatT, vperm);
    attn_kernel<<<512, 512, 0, stream>>>(qhat, khatT, vperm, oT);
    out_gemm<<<1024, 256, 0, stream>>>(oT, wob, x, out);
}

// Round 10
// 72.166 us; speedup vs baseline: 1.0494x; 1.0494x over previous
//
#include <hip/hip_runtime.h>
#include <hip/hip_bf16.h>

typedef short short4v __attribute__((ext_vector_type(4)));
typedef short short8v __attribute__((ext_vector_type(8)));
typedef float float4v __attribute__((ext_vector_type(4)));
typedef __bf16 bf16x8 __attribute__((ext_vector_type(8)));

typedef __attribute__((address_space(1))) const unsigned int g_uint;
typedef __attribute__((address_space(3))) unsigned int lds_uint;

__device__ __forceinline__ unsigned short f2bf(float f) {
    union { float f; unsigned int i; } t;
    t.f = f;
    unsigned int u = t.i;
    u += 0x7fffu + ((u >> 16) & 1u);   // round-to-nearest-even
    return (unsigned short)(u >> 16);
}

__device__ __forceinline__ short bfcast(float f) {
    __bf16 h = (__bf16)f;               // native cvt (compiler fuses pairs into v_cvt_pk_bf16_f32)
    return __builtin_bit_cast(short, h);
}

// v_exp_f32 computes 2^x; s_nop covers the trans->valu wait state
__device__ __forceinline__ float fast_exp2(float x) {
    float r;
    asm("v_exp_f32 %0, %1\n\ts_nop 0" : "=v"(r) : "v"(x));
    return r;
}

// async global->LDS, 16B per lane; lds dest is wave-uniform base + lane*16
__device__ __forceinline__ void gload_lds16(const unsigned short* g, unsigned short* l) {
    __builtin_amdgcn_global_load_lds((g_uint*)g, (lds_uint*)l, 16, 0, 0);
}

// read 8 contiguous bf16 (b128) from a swizzled [64][64] u16 tile:
// element (row, 8*slot + i) lives at u16 offset row*64 + ((slot ^ (row&7))<<3) + i
__device__ __forceinline__ bf16x8 frag128(const unsigned short* t, int row, int slot) {
    return *reinterpret_cast<const bf16x8*>(
        reinterpret_cast<const char*>(t) + row * 128 + (((slot ^ (row & 7)) << 4)));
}

__device__ __forceinline__ float4v mfma32(bf16x8 a, bf16x8 b, float4v c) {
    return __builtin_amdgcn_mfma_f32_16x16x32_bf16(a, b, c, 0, 0, 0);
}

// ---------------------------------------------------------------------------
// Kernel 0: weights f32 -> bf16
// ---------------------------------------------------------------------------
__global__ __launch_bounds__(256) void prep_kernel(const float* __restrict__ wq,
                                                   const float* __restrict__ wo,
                                                   unsigned short* __restrict__ wqb,
                                                   unsigned short* __restrict__ wob) {
    int i = blockIdx.x * 256 + threadIdx.x;   // 262144 total
    if (i < 196608) wqb[i] = f2bf(wq[i]);
    else            wob[i - 196608] = f2bf(wo[i - 196608]);
}

// ---------------------------------------------------------------------------
// Kernel 1: channel LayerNorm.  x[b][c=256][pix] f32 -> xn_T[b][pix][c] bf16.
// ---------------------------------------------------------------------------
__global__ __launch_bounds__(256) void ln_kernel(const float* __restrict__ x,
                                                 const float* __restrict__ g,
                                                 unsigned short* __restrict__ xnT) {
    __shared__ float red[2][4][64];
    const int tid = threadIdx.x;
    const int p = tid & 63, cg = tid >> 6;
    const int b = blockIdx.y;
    const int pix = blockIdx.x * 64 + p;
    const float* xb = x + ((size_t)b << 18) + pix;

    float v[64];
    float s = 0.f, q = 0.f;
    #pragma unroll
    for (int cc = 0; cc < 64; ++cc) {
        v[cc] = xb[(cg * 64 + cc) << 10];
        s += v[cc]; q += v[cc] * v[cc];
    }
    red[0][cg][p] = s; red[1][cg][p] = q;
    __syncthreads();
    float ts = red[0][0][p] + red[0][1][p] + red[0][2][p] + red[0][3][p];
    float tq = red[1][0][p] + red[1][1][p] + red[1][2][p] + red[1][3][p];
    float mean = ts * (1.f / 256.f);
    float var  = tq * (1.f / 256.f) - mean * mean;
    float rstd = rsqrtf(var + 1e-5f);
    float bias = -mean * rstd;

    unsigned short* dst = xnT + (((size_t)b << 10) + pix) * 256 + cg * 64;
    #pragma unroll
    for (int cc = 0; cc < 64; cc += 8) {
        union { uint4 u; unsigned short s[8]; } pk;
        #pragma unroll
        for (int j = 0; j < 8; ++j)
            pk.s[j] = f2bf(fmaf(v[cc + j], rstd, bias) * g[cg * 64 + cc + j]);
        *reinterpret_cast<uint4*>(dst + cc) = pk.u;
    }
}

// ---------------------------------------------------------------------------
// Kernel 2: QKV GEMM, fused L2-norm + attention-ready layouts.
// 1D grid 3072, XCD-swizzled.  (r6's proven 2-buffer structure.)
// m<4: qhat (scaled by 8*log2e); m 4..7: khatT swizzled tiles;
// m>=8: vperm swizzled tiles.
// ---------------------------------------------------------------------------
__global__ __launch_bounds__(256) void qkv_gemm(const unsigned short* __restrict__ xnT,
                                                const unsigned short* __restrict__ wqkv,
                                                unsigned short* __restrict__ qhat,
                                                unsigned short* __restrict__ khatT,
                                                unsigned short* __restrict__ vperm) {
    __shared__ __align__(16) unsigned short sW[8192];
    __shared__ __align__(16) unsigned short sX[8192];
    const int tid = threadIdx.x, lane = tid & 63, w = tid >> 6;
    const int l16 = lane & 15, g = lane >> 4;
    const int id = blockIdx.x;
    const int xcd = id & 7, sIdx = id >> 3;
    const int m = sIdx % 12, tq = sIdx / 12;
    const int t = xcd + (tq << 3);            // 0..255 X-tile index
    const int pb = t & 15, b = t >> 4;

    const unsigned short* Wbase = wqkv + m * 64 * 256;
    const unsigned short* Xbase = xnT + (((size_t)b << 10) + pb * 64) * 256;

    const int srow = (lane >> 3);
    const int sslot = lane & 7;

    auto stage = [&](int buf, int k0) {
        #pragma unroll
        for (int ii = 0; ii < 2; ++ii) {
            int inst = w + 4 * ii;
            int row = inst * 8 + srow;
            int src = row * 256 + k0 + 8 * (sslot ^ (row & 7));
            gload_lds16(Wbase + src, &sW[buf * 4096 + inst * 512]);
            gload_lds16(Xbase + src, &sX[buf * 4096 + inst * 512]);
        }
    };

    float4v acc[4] = {{0,0,0,0},{0,0,0,0},{0,0,0,0},{0,0,0,0}};
    const bool qk = (m < 8);

    stage(0, 0);
    __syncthreads();
    for (int ks = 0; ks < 4; ++ks) {
        if (ks < 3) stage((ks + 1) & 1, (ks + 1) * 64);
        const unsigned short* Wt = &sW[(ks & 1) * 4096];
        const unsigned short* Xt = &sX[(ks & 1) * 4096];
        #pragma unroll
        for (int kk = 0; kk < 2; ++kk) {
            bf16x8 aF = frag128(qk ? Xt : Wt, 16 * w + l16, 4 * kk + g);
            #pragma unroll
            for (int jt = 0; jt < 4; ++jt) {
                bf16x8 bF = frag128(qk ? Wt : Xt, 16 * jt + l16, 4 * kk + g);
                acc[jt] = mfma32(aF, bF, acc[jt]);
            }
        }
        __syncthreads();
    }

    if (qk) {
        // D[pix = pb*64 + 16w + 4g + r][d(head) = 16jt + l16]; l2-norm over d
        float rn[4];
        #pragma unroll
        for (int r = 0; r < 4; ++r) {
            float s = acc[0][r]*acc[0][r] + acc[1][r]*acc[1][r]
                    + acc[2][r]*acc[2][r] + acc[3][r]*acc[3][r];
            s += __shfl_xor(s, 1, 64);
            s += __shfl_xor(s, 2, 64);
            s += __shfl_xor(s, 4, 64);
            s += __shfl_xor(s, 8, 64);
            rn[r] = rsqrtf(fmaxf(s, 1e-24f));
        }
        int h = m & 3;
        int bh = b * 4 + h;
        if (m < 4) {
            // fold 8*log2(e) so attention can use p = exp2(st) with no bias
            unsigned short* qb = qhat + ((size_t)bh << 16) + (size_t)(pb * 64 + 16 * w) * 64;
            #pragma unroll
            for (int jt = 0; jt < 4; ++jt)
                #pragma unroll
                for (int r = 0; r < 4; ++r)
                    qb[(4 * g + r) * 64 + 16 * jt + l16] =
                        f2bf(acc[jt][r] * (rn[r] * 11.541560327111707f));
        } else {
            // swizzled K tile: element (j, d) at j*64 + ((d>>3 ^ (j&7))<<3) + (d&7)
            unsigned short* kb = khatT + ((size_t)(bh * 16 + pb)) * 4096;
            #pragma unroll
            for (int jt = 0; jt < 4; ++jt)
                #pragma unroll
                for (int r = 0; r < 4; ++r) {
                    int j = 16 * w + 4 * g + r;
                    int d = 16 * jt + l16;
                    kb[j * 64 + (((d >> 3) ^ (j & 7)) << 3) + (d & 7)] =
                        f2bf(acc[jt][r] * rn[r]);
                }
        }
    } else {
        // V tile [d][colperm(j)] with same XOR swizzle on the 16B slot
        int bh = b * 4 + (m - 8);
        unsigned short* vb = vperm + ((size_t)(bh * 16 + pb)) * 4096;
        #pragma unroll
        for (int jt = 0; jt < 4; ++jt) {
            int cphi = (l16 >> 2) * 2 + (jt >> 1);       // 16B-slot index of colperm(j)
            int cplo = (jt & 1) * 4 + (l16 & 3);         // position within slot
            #pragma unroll
            for (int r = 0; r < 4; ++r) {
                int d = 16 * w + 4 * g + r;
                vb[d * 64 + ((cphi ^ (d & 7)) << 3) + cplo] = f2bf(acc[jt][r]);
            }
        }
    }
}

// ---------------------------------------------------------------------------
// Kernel 3: flash attention, 32 queries/wave AND 4 waves/SIMD via j-split.
// grid 512 XCD-swizzled, 512 threads = 8 waves = 4 i-waves x 2 j-halves.
// Each j-half has its own double-buffered K|V LDS pair (4 x 16 KB = 64 KB);
// halves process tiles 0-7 / 8-15 independently (fixed-max softmax makes
// partial (oacc, lsum) exactly additive), combining through LDS at the end
// (r5's proven combine).  Inner 32q body = r8's proven code; staging = r6's
// proven stage->syncthreads.  Halves LDS reads AND barrier count vs r6.
// ---------------------------------------------------------------------------
__global__ __launch_bounds__(512, 4) void attn_kernel(const unsigned short* __restrict__ qhat,
                                                      const unsigned short* __restrict__ khatT,
                                                      const unsigned short* __restrict__ vperm,
                                                      unsigned short* __restrict__ oT) {
    // staging: buf(half,par) at u16 (half*2+par)*8192: K 4096 u16 | V 4096 u16.
    // After the loop the region is reused: OLf f32[128][68] | lsumS f32[128] |
    // OLb u16[128][72]  (53.8 KB of the 64 KB).
    __shared__ __align__(16) unsigned short smem[32768];
    const int tid = threadIdx.x, lane = tid & 63, w = tid >> 6;   // 0..7
    const int wi = w & 3, wg = w >> 2;        // i-quarter, j-half
    const int l16 = lane & 15, g = lane >> 4;
    const int id = blockIdx.x;
    const int sIdx = id >> 3;
    const int bh = (id & 7) * 8 + (sIdx >> 3);
    const int qb = sIdx & 7;
    const int b = bh >> 2, h = bh & 3;

    const unsigned short* Qg = qhat + ((size_t)bh << 16) + (size_t)(qb * 128) * 64;
    const unsigned short* Kt = khatT + ((size_t)(bh * 16)) * 4096;
    const unsigned short* Vt = vperm + ((size_t)(bh * 16)) * 4096;

    // Q fragments (B-operand of K=32 mfma): col i = 32*wi + 16*it + l16
    bf16x8 bq[2][2];
    #pragma unroll
    for (int it = 0; it < 2; ++it)
        #pragma unroll
        for (int ds = 0; ds < 2; ++ds)
            bq[it][ds] = *reinterpret_cast<const bf16x8*>(
                Qg + (32 * wi + 16 * it + l16) * 64 + 32 * ds + 8 * g);

    // wave stages quarter wi of its half's tile t: 4 gload_lds (2 K + 2 V)
    auto stage = [&](int par, int t) {
        unsigned short* kb = &smem[(wg * 2 + par) * 8192 + wi * 1024];
        unsigned short* vb = kb + 4096;
        const unsigned short* ks = Kt + t * 4096 + wi * 1024;
        const unsigned short* vs = Vt + t * 4096 + wi * 1024;
        gload_lds16(ks + lane * 8, kb);
        gload_lds16(ks + 512 + lane * 8, kb + 512);
        gload_lds16(vs + lane * 8, vb);
        gload_lds16(vs + 512 + lane * 8, vb + 512);
    };

    float lsum[2] = {0.f, 0.f};
    float4v oacc[2][4] = {};

    stage(0, 8 * wg);
    __syncthreads();

    for (int tt = 0; tt < 8; ++tt) {
        const unsigned short* kb = &smem[(wg * 2 + (tt & 1)) * 8192];
        const unsigned short* vb = kb + 4096;
        if (tt < 7) stage((tt + 1) & 1, 8 * wg + tt + 1);   // issue next early

        // S^T[j][i] = sum_d K[j][d] Q^T[d][i]   (16 MFMAs: 2ds x 4jt x 2it)
        float4v st[2][4] = {};
        #pragma unroll
        for (int ds = 0; ds < 2; ++ds) {
            bf16x8 ak[4];
            #pragma unroll
            for (int jt = 0; jt < 4; ++jt)
                ak[jt] = frag128(kb, 16 * jt + l16, 4 * ds + g);
            __builtin_amdgcn_s_setprio(1);
            #pragma unroll
            for (int jt = 0; jt < 4; ++jt)
                #pragma unroll
                for (int it = 0; it < 2; ++it)
                    st[it][jt] = mfma32(ak[jt], bq[it][ds], st[it][jt]);
            __builtin_amdgcn_s_setprio(0);
        }

        // V fragment ds_reads issued before softmax; exp hides their latency
        short8v vv[4][2];
        #pragma unroll
        for (int dt = 0; dt < 4; ++dt) {
            int row = 16 * dt + l16;
            #pragma unroll
            for (int q = 0; q < 2; ++q)
                vv[dt][q] = *reinterpret_cast<const short8v*>(
                    reinterpret_cast<const char*>(vb) + row * 128 +
                    (((2 * g + q) ^ (row & 7)) << 4));
        }

        // fixed-max softmax: p = exp2(st)
        short4v pf[2][4];
        #pragma unroll
        for (int it = 0; it < 2; ++it) {
            #pragma unroll
            for (int jt = 0; jt < 4; ++jt) {
                float p0 = fast_exp2(st[it][jt][0]);
                float p1 = fast_exp2(st[it][jt][1]);
                float p2 = fast_exp2(st[it][jt][2]);
                float p3 = fast_exp2(st[it][jt][3]);
                lsum[it] += (p0 + p1) + (p2 + p3);
                short4v tt2;
                tt2[0] = bfcast(p0); tt2[1] = bfcast(p1);
                tt2[2] = bfcast(p2); tt2[3] = bfcast(p3);
                pf[it][jt] = tt2;
            }
        }

        // O^T[d][i] += V^T[d][j] P^T[j][i]   (32 MFMAs)
        __builtin_amdgcn_s_setprio(1);
        #pragma unroll
        for (int dt = 0; dt < 4; ++dt)
            #pragma unroll
            for (int q = 0; q < 2; ++q) {
                short4v lo = __builtin_shufflevector(vv[dt][q], vv[dt][q], 0, 1, 2, 3);
                short4v hi = __builtin_shufflevector(vv[dt][q], vv[dt][q], 4, 5, 6, 7);
                #pragma unroll
                for (int it = 0; it < 2; ++it) {
                    oacc[it][dt] = __builtin_amdgcn_mfma_f32_16x16x16bf16_1k(
                        lo, pf[it][2 * q], oacc[it][dt], 0, 0, 0);
                    oacc[it][dt] = __builtin_amdgcn_mfma_f32_16x16x16bf16_1k(
                        hi, pf[it][2 * q + 1], oacc[it][dt], 0, 0, 0);
                }
            }
        __builtin_amdgcn_s_setprio(0);

        __syncthreads();   // buf consumed; next iter's stage may overwrite it
    }

    // per-half softmax denominators across the 4 lane-groups sharing column i
    #pragma unroll
    for (int it = 0; it < 2; ++it) {
        lsum[it] += __shfl_xor(lsum[it], 16, 64);
        lsum[it] += __shfl_xor(lsum[it], 32, 64);
    }

    // combine the two j-halves (exactly additive under fixed-max softmax)
    float* OLf = reinterpret_cast<float*>(smem);            // [128][68] f32
    float* lsumS = reinterpret_cast<float*>(smem) + 8704;   // [128] f32
    unsigned short* OLb = smem + 17664;                     // [128][72] u16

    if (wg == 0) {
        #pragma unroll
        for (int it = 0; it < 2; ++it) {
            int row = 32 * wi + 16 * it + l16;
            #pragma unroll
            for (int dt = 0; dt < 4; ++dt)
                *reinterpret_cast<float4v*>(&OLf[row * 68 + 16 * dt + 4 * g]) = oacc[it][dt];
            if (g == 0) lsumS[row] = lsum[it];
        }
    }
    __syncthreads();
    if (wg == 1) {
        #pragma unroll
        for (int it = 0; it < 2; ++it) {
            int row = 32 * wi + 16 * it + l16;
            float inv = 1.f / (lsumS[row] + lsum[it]);
            #pragma unroll
            for (int dt = 0; dt < 4; ++dt) {
                float4v o0 = *reinterpret_cast<const float4v*>(&OLf[row * 68 + 16 * dt + 4 * g]);
                #pragma unroll
                for (int r = 0; r < 4; ++r)
                    OLb[row * 72 + 16 * dt + 4 * g + r] =
                        f2bf((o0[r] + oacc[it][dt][r]) * inv);
            }
        }
    }
    __syncthreads();

    // coalesced store: O_T[pix][h*64+d]; 4 threads per row, 32B each
    {
        int row = tid >> 2, q4 = tid & 3;
        unsigned short* dst = oT + (((size_t)b << 10) + qb * 128 + row) * 256 + h * 64 + q4 * 16;
        const unsigned short* src = OLb + row * 72 + q4 * 16;
        *reinterpret_cast<uint4*>(dst)     = *reinterpret_cast<const uint4*>(src);
        *reinterpret_cast<uint4*>(dst + 8) = *reinterpret_cast<const uint4*>(src + 8);
    }
}

// ---------------------------------------------------------------------------
// Kernel 4: out projection + residual.  1D grid 1024, XCD-swizzled.
// (r6's proven 2-buffer structure.)
// ---------------------------------------------------------------------------
__global__ __launch_bounds__(256) void out_gemm(const unsigned short* __restrict__ oT,
                                                const unsigned short* __restrict__ wout,
                                                const float* __restrict__ x,
                                                float* __restrict__ out) {
    __shared__ __align__(16) unsigned short sW[8192];
    __shared__ __align__(16) unsigned short sX[8192];
    const int tid = threadIdx.x, lane = tid & 63, w = tid >> 6;
    const int l16 = lane & 15, g = lane >> 4;
    const int id = blockIdx.x;
    const int xcd = id & 7, sIdx = id >> 3;   // sIdx 0..127
    const int m = sIdx & 3, tq = sIdx >> 2;
    const int t = xcd + (tq << 3);
    const int pb = t & 15, b = t >> 4;

    const unsigned short* Wbase = wout + m * 64 * 256;
    const unsigned short* Xbase = oT + (((size_t)b << 10) + pb * 64) * 256;

    const int srow = (lane >> 3);
    const int sslot = lane & 7;

    auto stage = [&](int buf, int k0) {
        #pragma unroll
        for (int ii = 0; ii < 2; ++ii) {
            int inst = w + 4 * ii;
            int row = inst * 8 + srow;
            int src = row * 256 + k0 + 8 * (sslot ^ (row & 7));
            gload_lds16(Wbase + src, &sW[buf * 4096 + inst * 512]);
            gload_lds16(Xbase + src, &sX[buf * 4096 + inst * 512]);
        }
    };

    float4v acc[4] = {{0,0,0,0},{0,0,0,0},{0,0,0,0},{0,0,0,0}};
    stage(0, 0);
    __syncthreads();
    for (int ks = 0; ks < 4; ++ks) {
        if (ks < 3) stage((ks + 1) & 1, (ks + 1) * 64);
        const unsigned short* Wt = &sW[(ks & 1) * 4096];
        const unsigned short* Xt = &sX[(ks & 1) * 4096];
        #pragma unroll
        for (int kk = 0; kk < 2; ++kk) {
            bf16x8 aF = frag128(Wt, 16 * w + l16, 4 * kk + g);
            #pragma unroll
            for (int jt = 0; jt < 4; ++jt) {
                bf16x8 bF = frag128(Xt, 16 * jt + l16, 4 * kk + g);
                acc[jt] = mfma32(aF, bF, acc[jt]);
            }
        }
        __syncthreads();
    }

    #pragma unroll
    for (int jt = 0; jt < 4; ++jt)
        #pragma unroll
        for (int r = 0; r < 4; ++r) {
            size_t idx = ((size_t)b << 18) + (size_t)(m * 64 + 16 * w + 4 * g + r) * 1024
                       + pb * 64 + 16 * jt + l16;
            out[idx] = acc[jt][r] + x[idx];
        }
}

// ---------------------------------------------------------------------------
extern "C" void kernel_launch(void* const* d_in, const int* in_sizes, int n_in,
                              void* d_out, int out_size, void* d_ws, size_t ws_size,
                              hipStream_t stream) {
    const float* x  = (const float*)d_in[0];
    const float* g  = (const float*)d_in[1];
    const float* wq = (const float*)d_in[2];
    const float* wo = (const float*)d_in[3];
    float* out = (float*)d_out;

    char* ws = (char*)d_ws;
    // ws layout:
    //   [0, 8.4MB)        xn_T bf16 [16][1024][256]; reused as O_T after qkv_gemm
    //   [8.4, 16.8MB)     qhat bf16 [bh=64][1024][64]  (scaled by 8*log2e)
    //   [16.8, 25.2MB)    khatT swizzled tiles [bh=64][16][64*64]
    //   [25.2, 33.6MB)    vperm swizzled tiles [bh=64][16][64*64]
    //   [33.6MB, ...)     w_qkv bf16, w_out bf16
    unsigned short* xnT   = (unsigned short*)(ws);
    unsigned short* qhat  = (unsigned short*)(ws + 8388608);
    unsigned short* khatT = (unsigned short*)(ws + 16777216);
    unsigned short* vperm = (unsigned short*)(ws + 25165824);
    unsigned short* wqb   = (unsigned short*)(ws + 33554432);
    unsigned short* wob   = (unsigned short*)(ws + 33947648);
    unsigned short* oT    = xnT;   // reuse

    prep_kernel<<<1024, 256, 0, stream>>>(wq, wo, wqb, wob);
    ln_kernel<<<dim3(16, 16), 256, 0, stream>>>(x, g, xnT);
    qkv_gemm<<<3072, 256, 0, stream>>>(xnT, wqb, qhat, khatT, vperm);
    attn_kernel<<<512, 512, 0, stream>>>(qhat, khatT, vperm, oT);
    out_gemm<<<1024, 256, 0, stream>>>(oT, wob, x, out);
}

// Round 11
// 63.816 us; speedup vs baseline: 1.1868x; 1.1309x over previous
//
#include <hip/hip_runtime.h>
#include <hip/hip_bf16.h>

typedef short short4v __attribute__((ext_vector_type(4)));
typedef short short8v __attribute__((ext_vector_type(8)));
typedef float float4v __attribute__((ext_vector_type(4)));
typedef __bf16 bf16x8 __attribute__((ext_vector_type(8)));

typedef __attribute__((address_space(1))) const unsigned int g_uint;
typedef __attribute__((address_space(3))) unsigned int lds_uint;

__device__ __forceinline__ unsigned short f2bf(float f) {
    union { float f; unsigned int i; } t;
    t.f = f;
    unsigned int u = t.i;
    u += 0x7fffu + ((u >> 16) & 1u);   // round-to-nearest-even
    return (unsigned short)(u >> 16);
}

__device__ __forceinline__ short bfcast(float f) {
    __bf16 h = (__bf16)f;               // native cvt (compiler fuses pairs into v_cvt_pk_bf16_f32)
    return __builtin_bit_cast(short, h);
}

// v_exp_f32 computes 2^x; s_nop covers the trans->valu wait state
__device__ __forceinline__ float fast_exp2(float x) {
    float r;
    asm("v_exp_f32 %0, %1\n\ts_nop 0" : "=v"(r) : "v"(x));
    return r;
}

// async global->LDS, 16B per lane; lds dest is wave-uniform base + lane*16
__device__ __forceinline__ void gload_lds16(const unsigned short* g, unsigned short* l) {
    __builtin_amdgcn_global_load_lds((g_uint*)g, (lds_uint*)l, 16, 0, 0);
}

// read 8 contiguous bf16 (b128) from a swizzled [64][64] u16 tile:
// element (row, 8*slot + i) lives at u16 offset row*64 + ((slot ^ (row&7))<<3) + i
__device__ __forceinline__ bf16x8 frag128(const unsigned short* t, int row, int slot) {
    return *reinterpret_cast<const bf16x8*>(
        reinterpret_cast<const char*>(t) + row * 128 + (((slot ^ (row & 7)) << 4)));
}

__device__ __forceinline__ float4v mfma32(bf16x8 a, bf16x8 b, float4v c) {
    return __builtin_amdgcn_mfma_f32_16x16x32_bf16(a, b, c, 0, 0, 0);
}

// ---------------------------------------------------------------------------
// Kernel 1: channel LayerNorm (+ fused weight f32->bf16 conversion blocks).
// grid (16, 17): y<16 -> LN for batch y; y==16 -> weight conversion.
// x[b][c=256][pix] f32 -> xn_T[b][pix][c] bf16.
// ---------------------------------------------------------------------------
__global__ __launch_bounds__(256) void ln_prep_kernel(const float* __restrict__ x,
                                                      const float* __restrict__ g,
                                                      const float* __restrict__ wq,
                                                      const float* __restrict__ wo,
                                                      unsigned short* __restrict__ xnT,
                                                      unsigned short* __restrict__ wqb,
                                                      unsigned short* __restrict__ wob) {
    const int tid = threadIdx.x;
    if (blockIdx.y == 16) {
        // weight conversion: 16 blocks x 256 thr x 16 float4 = 262144 floats
        const int bx = blockIdx.x;
        const float* src = (bx < 12) ? wq : wo;
        unsigned short* dst = (bx < 12) ? wqb : wob;
        const int base4 = ((bx < 12) ? bx : bx - 12) * 4096;
        #pragma unroll
        for (int k = 0; k < 16; ++k) {
            int f4 = base4 + k * 256 + tid;
            float4 v = reinterpret_cast<const float4*>(src)[f4];
            uint2 pk;
            pk.x = (unsigned int)f2bf(v.x) | ((unsigned int)f2bf(v.y) << 16);
            pk.y = (unsigned int)f2bf(v.z) | ((unsigned int)f2bf(v.w) << 16);
            *reinterpret_cast<uint2*>(dst + (size_t)f4 * 4) = pk;
        }
        return;
    }

    __shared__ float red[2][4][64];
    const int p = tid & 63, cg = tid >> 6;
    const int b = blockIdx.y;
    const int pix = blockIdx.x * 64 + p;
    const float* xb = x + ((size_t)b << 18) + pix;

    float v[64];
    float s = 0.f, q = 0.f;
    #pragma unroll
    for (int cc = 0; cc < 64; ++cc) {
        v[cc] = xb[(cg * 64 + cc) << 10];
        s += v[cc]; q += v[cc] * v[cc];
    }
    red[0][cg][p] = s; red[1][cg][p] = q;
    __syncthreads();
    float ts = red[0][0][p] + red[0][1][p] + red[0][2][p] + red[0][3][p];
    float tq = red[1][0][p] + red[1][1][p] + red[1][2][p] + red[1][3][p];
    float mean = ts * (1.f / 256.f);
    float var  = tq * (1.f / 256.f) - mean * mean;
    float rstd = rsqrtf(var + 1e-5f);
    float bias = -mean * rstd;

    unsigned short* dst = xnT + (((size_t)b << 10) + pix) * 256 + cg * 64;
    #pragma unroll
    for (int cc = 0; cc < 64; cc += 8) {
        union { uint4 u; unsigned short s[8]; } pk;
        #pragma unroll
        for (int j = 0; j < 8; ++j)
            pk.s[j] = f2bf(fmaf(v[cc + j], rstd, bias) * g[cg * 64 + cc + j]);
        *reinterpret_cast<uint4*>(dst + cc) = pk.u;
    }
}

// ---------------------------------------------------------------------------
// Kernel 2: QKV GEMM, fused L2-norm + attention-ready layouts.
// 1D grid 3072, XCD-swizzled.  (r6's proven 2-buffer structure.)
// m<4: qhat (scaled by 8*log2e); m 4..7: khatT swizzled tiles;
// m>=8: vperm swizzled tiles.
// ---------------------------------------------------------------------------
__global__ __launch_bounds__(256) void qkv_gemm(const unsigned short* __restrict__ xnT,
                                                const unsigned short* __restrict__ wqkv,
                                                unsigned short* __restrict__ qhat,
                                                unsigned short* __restrict__ khatT,
                                                unsigned short* __restrict__ vperm) {
    __shared__ __align__(16) unsigned short sW[8192];
    __shared__ __align__(16) unsigned short sX[8192];
    const int tid = threadIdx.x, lane = tid & 63, w = tid >> 6;
    const int l16 = lane & 15, g = lane >> 4;
    const int id = blockIdx.x;
    const int xcd = id & 7, sIdx = id >> 3;
    const int m = sIdx % 12, tq = sIdx / 12;
    const int t = xcd + (tq << 3);            // 0..255 X-tile index
    const int pb = t & 15, b = t >> 4;

    const unsigned short* Wbase = wqkv + m * 64 * 256;
    const unsigned short* Xbase = xnT + (((size_t)b << 10) + pb * 64) * 256;

    const int srow = (lane >> 3);
    const int sslot = lane & 7;

    auto stage = [&](int buf, int k0) {
        #pragma unroll
        for (int ii = 0; ii < 2; ++ii) {
            int inst = w + 4 * ii;
            int row = inst * 8 + srow;
            int src = row * 256 + k0 + 8 * (sslot ^ (row & 7));
            gload_lds16(Wbase + src, &sW[buf * 4096 + inst * 512]);
            gload_lds16(Xbase + src, &sX[buf * 4096 + inst * 512]);
        }
    };

    float4v acc[4] = {{0,0,0,0},{0,0,0,0},{0,0,0,0},{0,0,0,0}};
    const bool qk = (m < 8);

    stage(0, 0);
    __syncthreads();
    for (int ks = 0; ks < 4; ++ks) {
        if (ks < 3) stage((ks + 1) & 1, (ks + 1) * 64);
        const unsigned short* Wt = &sW[(ks & 1) * 4096];
        const unsigned short* Xt = &sX[(ks & 1) * 4096];
        #pragma unroll
        for (int kk = 0; kk < 2; ++kk) {
            bf16x8 aF = frag128(qk ? Xt : Wt, 16 * w + l16, 4 * kk + g);
            #pragma unroll
            for (int jt = 0; jt < 4; ++jt) {
                bf16x8 bF = frag128(qk ? Wt : Xt, 16 * jt + l16, 4 * kk + g);
                acc[jt] = mfma32(aF, bF, acc[jt]);
            }
        }
        __syncthreads();
    }

    if (qk) {
        // D[pix = pb*64 + 16w + 4g + r][d(head) = 16jt + l16]; l2-norm over d
        float rn[4];
        #pragma unroll
        for (int r = 0; r < 4; ++r) {
            float s = acc[0][r]*acc[0][r] + acc[1][r]*acc[1][r]
                    + acc[2][r]*acc[2][r] + acc[3][r]*acc[3][r];
            s += __shfl_xor(s, 1, 64);
            s += __shfl_xor(s, 2, 64);
            s += __shfl_xor(s, 4, 64);
            s += __shfl_xor(s, 8, 64);
            rn[r] = rsqrtf(fmaxf(s, 1e-24f));
        }
        int h = m & 3;
        int bh = b * 4 + h;
        if (m < 4) {
            // fold 8*log2(e) so attention can use p = exp2(st) with no bias
            unsigned short* qb = qhat + ((size_t)bh << 16) + (size_t)(pb * 64 + 16 * w) * 64;
            #pragma unroll
            for (int jt = 0; jt < 4; ++jt)
                #pragma unroll
                for (int r = 0; r < 4; ++r)
                    qb[(4 * g + r) * 64 + 16 * jt + l16] =
                        f2bf(acc[jt][r] * (rn[r] * 11.541560327111707f));
        } else {
            // swizzled K tile: element (j, d) at j*64 + ((d>>3 ^ (j&7))<<3) + (d&7)
            unsigned short* kb = khatT + ((size_t)(bh * 16 + pb)) * 4096;
            #pragma unroll
            for (int jt = 0; jt < 4; ++jt)
                #pragma unroll
                for (int r = 0; r < 4; ++r) {
                    int j = 16 * w + 4 * g + r;
                    int d = 16 * jt + l16;
                    kb[j * 64 + (((d >> 3) ^ (j & 7)) << 3) + (d & 7)] =
                        f2bf(acc[jt][r] * rn[r]);
                }
        }
    } else {
        // V tile [d][colperm(j)] with same XOR swizzle on the 16B slot
        int bh = b * 4 + (m - 8);
        unsigned short* vb = vperm + ((size_t)(bh * 16 + pb)) * 4096;
        #pragma unroll
        for (int jt = 0; jt < 4; ++jt) {
            int cphi = (l16 >> 2) * 2 + (jt >> 1);       // 16B-slot index of colperm(j)
            int cplo = (jt & 1) * 4 + (l16 & 3);         // position within slot
            #pragma unroll
            for (int r = 0; r < 4; ++r) {
                int d = 16 * w + 4 * g + r;
                vb[d * 64 + ((cphi ^ (d & 7)) << 3) + cplo] = f2bf(acc[jt][r]);
            }
        }
    }
}

// ---------------------------------------------------------------------------
// Kernel 3: flash attention — r6's proven structure, verbatim.
// grid 512 XCD-swizzled, 512 threads = 8 waves; wave owns one 16-query i-tile.
// K+V tile (16 KB) staged once per block, double-buffered, stage->sync.
// Fixed-max softmax (q pre-scaled by 8*log2e): p = exp2(st), no rescale.
// ---------------------------------------------------------------------------
__global__ __launch_bounds__(512, 4) void attn_kernel(const unsigned short* __restrict__ qhat,
                                                      const unsigned short* __restrict__ khatT,
                                                      const unsigned short* __restrict__ vperm,
                                                      unsigned short* __restrict__ oT) {
    __shared__ __align__(16) unsigned short smem[16384];   // 2 x (K 4096 | V 4096)
    const int tid = threadIdx.x, lane = tid & 63, w = tid >> 6;
    const int l16 = lane & 15, g = lane >> 4;
    const int id = blockIdx.x;
    const int sIdx = id >> 3;
    const int bh = (id & 7) * 8 + (sIdx >> 3);
    const int qb = sIdx & 7;
    const int b = bh >> 2, h = bh & 3;

    const unsigned short* Qg = qhat + ((size_t)bh << 16) + (size_t)(qb * 128) * 64;
    const unsigned short* Kt = khatT + ((size_t)(bh * 16)) * 4096;
    const unsigned short* Vt = vperm + ((size_t)(bh * 16)) * 4096;

    // Q fragment (B-operand of K=32 mfma): col i = l16 of this wave's i-tile
    bf16x8 bq[2];
    #pragma unroll
    for (int ds = 0; ds < 2; ++ds)
        bq[ds] = *reinterpret_cast<const bf16x8*>(
            Qg + (16 * w + l16) * 64 + 32 * ds + 8 * g);

    auto stage = [&](int buf, int t) {      // 2 gloads per wave
        unsigned short* kb = &smem[buf * 8192 + w * 512];
        unsigned short* vb = &smem[buf * 8192 + 4096 + w * 512];
        gload_lds16(Kt + t * 4096 + w * 512 + lane * 8, kb);
        gload_lds16(Vt + t * 4096 + w * 512 + lane * 8, vb);
    };

    float lsum = 0.f;
    float4v oacc[4] = {};

    stage(0, 0);
    __syncthreads();

    for (int t = 0; t < 16; ++t) {
        const unsigned short* kb = &smem[(t & 1) * 8192];
        const unsigned short* vb = kb + 4096;
        if (t < 15) stage((t + 1) & 1, t + 1);   // issue next tile's loads early

        // S^T[j][i] = sum_d K[j][d] Q^T[d][i]
        float4v st[4] = {};
        #pragma unroll
        for (int ds = 0; ds < 2; ++ds) {
            bf16x8 ak[4];
            #pragma unroll
            for (int jt = 0; jt < 4; ++jt)
                ak[jt] = frag128(kb, 16 * jt + l16, 4 * ds + g);
            __builtin_amdgcn_s_setprio(1);
            #pragma unroll
            for (int jt = 0; jt < 4; ++jt)
                st[jt] = mfma32(ak[jt], bq[ds], st[jt]);
            __builtin_amdgcn_s_setprio(0);
        }

        // V fragment ds_reads issued before softmax; exp hides their latency
        short8v vv[4][2];
        #pragma unroll
        for (int dt = 0; dt < 4; ++dt) {
            int row = 16 * dt + l16;
            #pragma unroll
            for (int q = 0; q < 2; ++q)
                vv[dt][q] = *reinterpret_cast<const short8v*>(
                    reinterpret_cast<const char*>(vb) + row * 128 +
                    (((2 * g + q) ^ (row & 7)) << 4));
        }

        // fixed-max softmax: p = exp2(st)
        short4v pf[4];
        #pragma unroll
        for (int jt = 0; jt < 4; ++jt) {
            float p0 = fast_exp2(st[jt][0]);
            float p1 = fast_exp2(st[jt][1]);
            float p2 = fast_exp2(st[jt][2]);
            float p3 = fast_exp2(st[jt][3]);
            lsum += (p0 + p1) + (p2 + p3);
            short4v tt;
            tt[0] = bfcast(p0); tt[1] = bfcast(p1);
            tt[2] = bfcast(p2); tt[3] = bfcast(p3);
            pf[jt] = tt;
        }

        // O^T[d][i] += V^T[d][j] P^T[j][i]
        __builtin_amdgcn_s_setprio(1);
        #pragma unroll
        for (int dt = 0; dt < 4; ++dt)
            #pragma unroll
            for (int q = 0; q < 2; ++q) {
                short4v lo = __builtin_shufflevector(vv[dt][q], vv[dt][q], 0, 1, 2, 3);
                short4v hi = __builtin_shufflevector(vv[dt][q], vv[dt][q], 4, 5, 6, 7);
                oacc[dt] = __builtin_amdgcn_mfma_f32_16x16x16bf16_1k(
                    lo, pf[2 * q], oacc[dt], 0, 0, 0);
                oacc[dt] = __builtin_amdgcn_mfma_f32_16x16x16bf16_1k(
                    hi, pf[2 * q + 1], oacc[dt], 0, 0, 0);
            }
        __builtin_amdgcn_s_setprio(0);

        __syncthreads();   // buf consumed; next iter's stage may overwrite it
    }

    // softmax denominator across the 4 lane-groups sharing column i
    lsum += __shfl_xor(lsum, 16, 64);
    lsum += __shfl_xor(lsum, 32, 64);
    float inv = 1.f / lsum;

    // transpose O through LDS (reuse smem) -> O_T[pix][h*64+d]
    unsigned short* OL = smem;   // [128][72] u16
    {
        int irow = 16 * w + l16;
        #pragma unroll
        for (int dt = 0; dt < 4; ++dt)
            #pragma unroll
            for (int r = 0; r < 4; ++r)
                OL[irow * 72 + 16 * dt + 4 * g + r] = f2bf(oacc[dt][r] * inv);
    }
    __syncthreads();
    {
        int row = tid >> 2, q4 = tid & 3;
        unsigned short* dst = oT + (((size_t)b << 10) + qb * 128 + row) * 256 + h * 64 + q4 * 16;
        const unsigned short* src = OL + row * 72 + q4 * 16;
        *reinterpret_cast<uint4*>(dst)     = *reinterpret_cast<const uint4*>(src);
        *reinterpret_cast<uint4*>(dst + 8) = *reinterpret_cast<const uint4*>(src + 8);
    }
}

// ---------------------------------------------------------------------------
// Kernel 4: out projection + residual.  1D grid 1024, XCD-swizzled.
// (r6's proven 2-buffer structure.)
// ---------------------------------------------------------------------------
__global__ __launch_bounds__(256) void out_gemm(const unsigned short* __restrict__ oT,
                                                const unsigned short* __restrict__ wout,
                                                const float* __restrict__ x,
                                                float* __restrict__ out) {
    __shared__ __align__(16) unsigned short sW[8192];
    __shared__ __align__(16) unsigned short sX[8192];
    const int tid = threadIdx.x, lane = tid & 63, w = tid >> 6;
    const int l16 = lane & 15, g = lane >> 4;
    const int id = blockIdx.x;
    const int xcd = id & 7, sIdx = id >> 3;   // sIdx 0..127
    const int m = sIdx & 3, tq = sIdx >> 2;
    const int t = xcd + (tq << 3);
    const int pb = t & 15, b = t >> 4;

    const unsigned short* Wbase = wout + m * 64 * 256;
    const unsigned short* Xbase = oT + (((size_t)b << 10) + pb * 64) * 256;

    const int srow = (lane >> 3);
    const int sslot = lane & 7;

    auto stage = [&](int buf, int k0) {
        #pragma unroll
        for (int ii = 0; ii < 2; ++ii) {
            int inst = w + 4 * ii;
            int row = inst * 8 + srow;
            int src = row * 256 + k0 + 8 * (sslot ^ (row & 7));
            gload_lds16(Wbase + src, &sW[buf * 4096 + inst * 512]);
            gload_lds16(Xbase + src, &sX[buf * 4096 + inst * 512]);
        }
    };

    float4v acc[4] = {{0,0,0,0},{0,0,0,0},{0,0,0,0},{0,0,0,0}};
    stage(0, 0);
    __syncthreads();
    for (int ks = 0; ks < 4; ++ks) {
        if (ks < 3) stage((ks + 1) & 1, (ks + 1) * 64);
        const unsigned short* Wt = &sW[(ks & 1) * 4096];
        const unsigned short* Xt = &sX[(ks & 1) * 4096];
        #pragma unroll
        for (int kk = 0; kk < 2; ++kk) {
            bf16x8 aF = frag128(Wt, 16 * w + l16, 4 * kk + g);
            #pragma unroll
            for (int jt = 0; jt < 4; ++jt) {
                bf16x8 bF = frag128(Xt, 16 * jt + l16, 4 * kk + g);
                acc[jt] = mfma32(aF, bF, acc[jt]);
            }
        }
        __syncthreads();
    }

    #pragma unroll
    for (int jt = 0; jt < 4; ++jt)
        #pragma unroll
        for (int r = 0; r < 4; ++r) {
            size_t idx = ((size_t)b << 18) + (size_t)(m * 64 + 16 * w + 4 * g + r) * 1024
                       + pb * 64 + 16 * jt + l16;
            out[idx] = acc[jt][r] + x[idx];
        }
}

// ---------------------------------------------------------------------------
extern "C" void kernel_launch(void* const* d_in, const int* in_sizes, int n_in,
                              void* d_out, int out_size, void* d_ws, size_t ws_size,
                              hipStream_t stream) {
    const float* x  = (const float*)d_in[0];
    const float* g  = (const float*)d_in[1];
    const float* wq = (const float*)d_in[2];
    const float* wo = (const float*)d_in[3];
    float* out = (float*)d_out;

    char* ws = (char*)d_ws;
    // ws layout:
    //   [0, 8.4MB)        xn_T bf16 [16][1024][256]; reused as O_T after qkv_gemm
    //   [8.4, 16.8MB)     qhat bf16 [bh=64][1024][64]  (scaled by 8*log2e)
    //   [16.8, 25.2MB)    khatT swizzled tiles [bh=64][16][64*64]
    //   [25.2, 33.6MB)    vperm swizzled tiles [bh=64][16][64*64]
    //   [33.6MB, ...)     w_qkv bf16, w_out bf16
    unsigned short* xnT   = (unsigned short*)(ws);
    unsigned short* qhat  = (unsigned short*)(ws + 8388608);
    unsigned short* khatT = (unsigned short*)(ws + 16777216);
    unsigned short* vperm = (unsigned short*)(ws + 25165824);
    unsigned short* wqb   = (unsigned short*)(ws + 33554432);
    unsigned short* wob   = (unsigned short*)(ws + 33947648);
    unsigned short* oT    = xnT;   // reuse

    ln_prep_kernel<<<dim3(16, 17), 256, 0, stream>>>(x, g, wq, wo, xnT, wqb, wob);
    qkv_gemm<<<3072, 256, 0, stream>>>(xnT, wqb, qhat, khatT, vperm);
    attn_kernel<<<512, 512, 0, stream>>>(qhat, khatT, vperm, oT);
    out_gemm<<<1024, 256, 0, stream>>>(oT, wob, x, out);
}